// Round 1
// 249.160 us; speedup vs baseline: 1.0069x; 1.0069x over previous
//
#include <hip/hip_runtime.h>

typedef unsigned short ushort_t;
typedef __attribute__((ext_vector_type(8))) short bf8_t;   // 8 x bf16 (4 VGPRs)
typedef __attribute__((ext_vector_type(4))) float f4_t;    // MFMA acc

#define B_   4096
#define IN_  1024
#define H_   1024
#define F_   128
#define G4_  4096
#define EPS_ 1e-5f

#define NG1   512   // gemm1 blocks in stageA
#define NPREP 256   // prep blocks
#define NGRAM 128   // gram blocks

__device__ __forceinline__ float us2f(unsigned short s) {
  union { unsigned int u; float f; } v;
  v.u = ((unsigned int)s) << 16;
  return v.f;
}
__device__ __forceinline__ unsigned short f2us(float f) {  // fp32 -> bf16 RNE
  union { float f; unsigned int u; } v;
  v.f = f;
  unsigned int r = (v.u + 0x7fffu + ((v.u >> 16) & 1u)) >> 16;
  return (unsigned short)r;
}
__device__ __forceinline__ float sigf(float x) { return 1.0f / (1.0f + __expf(-x)); }
__device__ __forceinline__ float tanh_f(float x) { return 1.0f - 2.0f / (1.0f + __expf(2.0f * x)); }

// Runtime input-dtype detection (R1/R2 A/B proved fp32; keep as insurance).
__device__ __forceinline__ int detect_fp32(const void* disc) {
  return ((const unsigned int*)disc)[0] == 0x3F800000u;
}
__device__ __forceinline__ float ldf(const void* p, int i, int fp32) {
  return fp32 ? ((const float*)p)[i] : us2f(((const ushort_t*)p)[i]);
}
__device__ __forceinline__ void ld8(const void* p, int idx, float* o, int fp32) {
  if (fp32) {
    const float4* q = (const float4*)((const float*)p + idx);
    float4 v0 = q[0], v1 = q[1];
    o[0]=v0.x; o[1]=v0.y; o[2]=v0.z; o[3]=v0.w;
    o[4]=v1.x; o[5]=v1.y; o[6]=v1.z; o[7]=v1.w;
  } else {
    uint4 v = *(const uint4*)((const ushort_t*)p + idx);
    const ushort_t* pv = (const ushort_t*)&v;
    #pragma unroll
    for (int i = 0; i < 8; i++) o[i] = us2f(pv[i]);
  }
}
// fast fp32x8 -> bf16x8: round-half-up + v_perm_b32 byte pack (1.5 op/elem)
__device__ __forceinline__ bf8_t cvt8p(const float* f) {
  union { bf8_t v; unsigned int u[4]; } r;
  const unsigned int* ui = (const unsigned int*)f;
  #pragma unroll
  for (int i = 0; i < 4; i++) {
    unsigned int lo = ui[2 * i] + 0x8000u;
    unsigned int hi = ui[2 * i + 1] + 0x8000u;
    r.u[i] = __builtin_amdgcn_perm(hi, lo, 0x07060302u);
  }
  return r.v;
}

// ---------------------------------------------------------------------------
// stageA: three independent jobs fused into one launch for co-residency.
//  (unchanged from R6 except launch_bounds: cap occupancy target at 4
//   blocks/CU so the VGPR budget is 128/thread, not 64 -> no scratch spill)
// ---------------------------------------------------------------------------
__global__ __launch_bounds__(256, 4) void k_stageA(
    const void* __restrict__ X0, const void* __restrict__ X1,
    const void* __restrict__ Wc0, const void* __restrict__ Wc1,
    const void* __restrict__ topic,
    const void* __restrict__ thw0, const void* __restrict__ thw1,
    const void* __restrict__ thb0, const void* __restrict__ thb1,
    const void* __restrict__ wsb0, const void* __restrict__ wsb1,
    const void* __restrict__ Ai, const void* __restrict__ Ah,
    const void* __restrict__ lnwi, const void* __restrict__ lnwh,
    ushort_t* __restrict__ wb,
    float* __restrict__ cm_i, float* __restrict__ cm_h,
    float* __restrict__ g_i, float* __restrict__ g_h,
    float* __restrict__ C0, float* __restrict__ C1)
{
  __shared__ float smem[32 * 128];   // used by gram branch only
  int bid = blockIdx.x, tid = threadIdx.x;
  int fp32 = detect_fp32(lnwi);

  if (bid < NG1) {
    int rb = bid >> 1, mat = bid & 1;
    const void* X   = mat ? X1 : X0;
    const void* W   = mat ? Wc1 : Wc0;
    const void* thw = mat ? thw1 : thw0;
    const void* thb = mat ? thb1 : thb0;
    const void* wbp = mat ? wsb1 : wsb0;
    float* C = mat ? C1 : C0;
    int lane = tid & 63, w = tid >> 6;
    int quad = lane >> 4, lcol = lane & 15;
    int brow0 = rb * 16;

    f4_t acc[2];
    acc[0] = (f4_t){0.f, 0.f, 0.f, 0.f};
    acc[1] = (f4_t){0.f, 0.f, 0.f, 0.f};

    #pragma unroll 4
    for (int kc = 0; kc < 32; kc++) {
      int kb = kc * 32 + quad * 8;
      float a[8];
      ld8(X, (brow0 + lcol) * IN_ + kb, a, fp32);
      bf8_t af = cvt8p(a);
      #pragma unroll
      for (int t = 0; t < 2; t++) {
        float bt[8];
        ld8(W, ((w * 2 + t) * 16 + lcol) * IN_ + kb, bt, fp32);
        acc[t] = __builtin_amdgcn_mfma_f32_16x16x32_bf16(af, cvt8p(bt), acc[t], 0, 0, 0);
      }
    }

    float thwf[3][3], thbf[3];
    #pragma unroll
    for (int t = 0; t < 3; t++) {
      thbf[t] = ldf(thb, t, fp32);
      #pragma unroll
      for (int t2 = 0; t2 < 3; t2++) thwf[t][t2] = ldf(thw, t * 3 + t2, fp32);
    }
    float tmpv[4][3];
    #pragma unroll
    for (int reg = 0; reg < 4; reg++) {
      int b = brow0 + quad * 4 + reg;
      float tp0 = ldf(topic, b * 3 + 0, fp32);
      float tp1 = ldf(topic, b * 3 + 1, fp32);
      float tp2 = ldf(topic, b * 3 + 2, fp32);
      #pragma unroll
      for (int t = 0; t < 3; t++)
        tmpv[reg][t] = thbf[t] + tp0 * thwf[t][0] + tp1 * thwf[t][1] + tp2 * thwf[t][2];
    }
    #pragma unroll
    for (int t = 0; t < 2; t++) {
      int f = (w * 2 + t) * 16 + lcol;
      float wv0 = ldf(wbp, f * 3 + 0, fp32);
      float wv1 = ldf(wbp, f * 3 + 1, fp32);
      float wv2 = ldf(wbp, f * 3 + 2, fp32);
      #pragma unroll
      for (int reg = 0; reg < 4; reg++) {
        float sc = tmpv[reg][0] * wv0 + tmpv[reg][1] * wv1 + tmpv[reg][2] * wv2;
        C[(brow0 + quad * 4 + reg) * F_ + f] = acc[t][reg] * sc;
      }
    }
  } else if (bid < NG1 + NPREP) {
    int t = bid - NG1;
    #pragma unroll
    for (int i = 0; i < 16; i++) {
      int e = i * 256 + tid;
      int c = e >> 9, l = (e >> 3) & 63, j = e & 7;
      int k = c * 32 + ((l >> 4) << 3) + j;
      int n = t * 16 + (l & 15);
      float v;
      if (k < 128) v = ldf(Ai, n * F_ + k, fp32) * ldf(lnwi, n, fp32);
      else         v = ldf(Ah, n * F_ + (k - 128), fp32) * ldf(lnwh, n, fp32);
      wb[(size_t)t * 4096 + e] = f2us(v);
    }
    const void* A = (tid < 128) ? Ai : Ah;
    float* cm = (tid < 128) ? cm_i : cm_h;
    int f = tid & 127;
    float s = 0.f;
    #pragma unroll
    for (int i = 0; i < 16; i++) s += ldf(A, (t * 16 + i) * F_ + f, fp32);
    atomicAdd(&cm[f], s);
  } else {
    int g = bid - (NG1 + NPREP);
    int fblk = g & 3, mat = (g >> 2) & 1, z = g >> 3;
    const void* A = mat ? Ah : Ai;
    float* G = mat ? g_h : g_i;
    float (*As)[128] = (float(*)[128])smem;
    int f1_0 = fblk * 32;
    int tf2 = tid & 31, tf1 = tid >> 5;
    float acc[4][4] = {};
    int nbase = z * 256;
    for (int n0 = nbase; n0 < nbase + 256; n0 += 32) {
      #pragma unroll
      for (int j = 0; j < 2; j++) {
        int idx = tid + 256 * j;
        int nn = idx >> 4, f8 = (idx & 15) * 8;
        float t[8];
        ld8(A, (n0 + nn) * F_ + f8, t, fp32);
        #pragma unroll
        for (int i = 0; i < 8; i++) As[nn][f8 + i] = t[i];
      }
      __syncthreads();
      #pragma unroll 4
      for (int nn = 0; nn < 32; nn++) {
        float4 a1 = *(const float4*)&As[nn][f1_0 + 4 * tf1];
        float4 a2 = *(const float4*)&As[nn][4 * tf2];
        const float* x1 = (const float*)&a1;
        const float* x2 = (const float*)&a2;
        #pragma unroll
        for (int i = 0; i < 4; i++)
          #pragma unroll
          for (int j = 0; j < 4; j++) acc[i][j] += x1[i] * x2[j];
      }
      __syncthreads();
    }
    #pragma unroll
    for (int i = 0; i < 4; i++)
      #pragma unroll
      for (int j = 0; j < 4; j++)
        atomicAdd(&G[(f1_0 + 4 * tf1 + i) * F_ + 4 * tf2 + j], acc[i][j]);
  }
}

// ---------------------------------------------------------------------------
// stats2: per-row LN stats via quadratic form (unchanged from R6 except
// launch_bounds 4 blocks/CU -> 128 VGPR budget)
// ---------------------------------------------------------------------------
__global__ __launch_bounds__(256, 4) void k_stats2(
    const float* __restrict__ C0, const float* __restrict__ C1,
    const float* __restrict__ g_i, const float* __restrict__ g_h,
    const float* __restrict__ cm_i, const float* __restrict__ cm_h,
    float* __restrict__ mrs_i, float* __restrict__ mrs_h,
    ushort_t* __restrict__ xb)
{
  int bid = blockIdx.x;
  int rb = bid >> 1, mat = bid & 1;
  const float* C  = mat ? C1 : C0;
  const float* G  = mat ? g_h : g_i;
  const float* cm = mat ? cm_h : cm_i;
  float* mrs = mat ? mrs_h : mrs_i;
  int kbase = mat ? 128 : 0;

  int tid = threadIdx.x;
  int lane = tid & 63, w = tid >> 6;
  int quad = lane >> 4, lcol = lane & 15;
  int b0 = rb * 16;

  __shared__ float p1part[4][16];
  __shared__ float p2s[16];
  __shared__ float rs_s[16];

  bf8_t af[4];
  float p2p = 0.f;
  #pragma unroll
  for (int kc = 0; kc < 4; kc++) {
    int kb = kc * 32 + quad * 8;
    const float4* q = (const float4*)(C + (b0 + lcol) * F_ + kb);
    float4 v0 = q[0], v1 = q[1];
    float a[8] = {v0.x, v0.y, v0.z, v0.w, v1.x, v1.y, v1.z, v1.w};
    af[kc] = cvt8p(a);
    if (w == 0) {
      #pragma unroll
      for (int j = 0; j < 8; j++) p2p += a[j] * cm[kb + j];
    }
  }

  float p1p[4] = {0.f, 0.f, 0.f, 0.f};
  #pragma unroll
  for (int t = 0; t < 2; t++) {
    int colf = (w * 2 + t) * 16 + lcol;
    f4_t acc = {0.f, 0.f, 0.f, 0.f};
    #pragma unroll
    for (int kc = 0; kc < 4; kc++) {
      const float4* qg = (const float4*)(G + colf * F_ + kc * 32 + quad * 8);
      float4 w0 = qg[0], w1 = qg[1];
      float bt[8] = {w0.x, w0.y, w0.z, w0.w, w1.x, w1.y, w1.z, w1.w};
      acc = __builtin_amdgcn_mfma_f32_16x16x32_bf16(af[kc], cvt8p(bt), acc, 0, 0, 0);
    }
    #pragma unroll
    for (int reg = 0; reg < 4; reg++)
      p1p[reg] += acc[reg] * C[(b0 + quad * 4 + reg) * F_ + colf];
  }
  #pragma unroll
  for (int d = 1; d < 16; d <<= 1)
    #pragma unroll
    for (int reg = 0; reg < 4; reg++)
      p1p[reg] += __shfl_xor(p1p[reg], d, 64);
  if (lcol == 0) {
    #pragma unroll
    for (int reg = 0; reg < 4; reg++)
      p1part[w][quad * 4 + reg] = p1p[reg];
  }
  if (w == 0) {
    p2p += __shfl_xor(p2p, 16, 64);
    p2p += __shfl_xor(p2p, 32, 64);
    if (quad == 0) p2s[lcol] = p2p;
  }
  __syncthreads();
  if (tid < 16) {
    float p1 = p1part[0][tid] + p1part[1][tid] + p1part[2][tid] + p1part[3][tid];
    float E2 = p1 * (1.0f / 4096.0f);
    float mu = p2s[tid] * (1.0f / 4096.0f);
    float var = E2 - mu * mu;
    float rs = rsqrtf(var + EPS_);
    rs_s[tid] = rs;
    mrs[b0 + tid] = mu * rs;
  }
  __syncthreads();
  int f = tid & 127, half = tid >> 7;
  ushort_t* xbb = xb + (size_t)rb * 4096;
  int k = kbase + f;
  int c = k >> 5, lq = (k >> 3) & 3, j = k & 7;
  #pragma unroll
  for (int i = 0; i < 8; i++) {
    int r2 = half * 8 + i;
    int lfrag = r2 | (lq << 4);
    xbb[c * 512 + lfrag * 8 + j] = f2us(C[(b0 + r2) * F_ + f] * rs_s[r2]);
  }
}

// ---------------------------------------------------------------------------
// K6 v4 (MFMA + coalesced I/O): 16 rows x 1024 cols per block, 16 waves.
// R7 change: __launch_bounds__(1024, 4). Without the 2nd arg the backend
// derives an occupancy target of 2 blocks/CU from the 68KB LDS (8 waves/EU)
// and caps VGPRs at 64 -> ~35 regs spilled to scratch per thread ->
// ~60MB extra WRITE + ~28MB extra FETCH (the amplification R6 chased in the
// store path). Grid is 256 = 1 block/CU, so 4 waves/EU (128 VGPR) is free.
// ---------------------------------------------------------------------------
__global__ __launch_bounds__(1024, 4) void k_fused(
    const ushort_t* __restrict__ xb, const ushort_t* __restrict__ wb,
    const float* __restrict__ mrs_i, const float* __restrict__ mrs_h,
    const void* __restrict__ lniw, const void* __restrict__ lnib,
    const void* __restrict__ lnhw, const void* __restrict__ lnhb,
    const void* __restrict__ lncw, const void* __restrict__ lncb,
    const void* __restrict__ cx, float* __restrict__ out)
{
  __shared__ float buf[16][1028];
  __shared__ float wpart[16][16][2];
  __shared__ float mu_s[16], rs_s[16];
  int tid = threadIdx.x;
  int lane = tid & 63, w = tid >> 6;
  int quad = lane >> 4, lcol = lane & 15;
  int b0 = blockIdx.x * 16;
  int fp32 = detect_fp32(lniw);

  // ---- stage cx into LDS, fully coalesced (2 passes x 8 floats/thread) ----
  #pragma unroll
  for (int pass = 0; pass < 2; pass++) {
    int e = pass * 8192 + tid * 8;
    int r = e >> 10, c = e & 1023;
    float t[8];
    ld8(cx, (b0 + r) * H_ + c, t, fp32);
    *(float4*)&buf[r][c] = *(float4*)&t[0];
    *(float4*)&buf[r][c + 4] = *(float4*)&t[4];
  }

  // A-fragments for this block's 16 rows (shared by all waves)
  const ushort_t* xblk = xb + (size_t)blockIdx.x * 4096;
  bf8_t af[8];
  #pragma unroll
  for (int c = 0; c < 8; c++)
    af[c] = *(const bf8_t*)(xblk + c * 512 + lane * 8);

  float mi[4], mh[4];
  #pragma unroll
  for (int reg = 0; reg < 4; reg++) {
    mi[reg] = mrs_i[b0 + quad * 4 + reg];
    mh[reg] = mrs_h[b0 + quad * 4 + reg];
  }
  __syncthreads();

  float val[4][4], okeep[4][4];

  #pragma unroll
  for (int q = 0; q < 4; q++) {
    int cg = w * 4 + q;
    int col = cg * 16 + lcol;
    f4_t accg[4];
    #pragma unroll
    for (int g = 0; g < 4; g++) {
      f4_t acc = {0.f, 0.f, 0.f, 0.f};
      int t = g * 64 + cg;
      const ushort_t* wt = wb + (size_t)t * 4096 + lane * 8;
      #pragma unroll
      for (int c = 0; c < 8; c++) {
        bf8_t bf = *(const bf8_t*)(wt + c * 512);
        acc = __builtin_amdgcn_mfma_f32_16x16x32_bf16(af[c], bf, acc, 0, 0, 0);
      }
      accg[g] = acc;
    }
    float liw0 = ldf(lniw, 0 * H_ + col, fp32), lib0 = ldf(lnib, 0 * H_ + col, fp32);
    float lhw0 = ldf(lnhw, 0 * H_ + col, fp32), lhb0 = ldf(lnhb, 0 * H_ + col, fp32);
    float liw1 = ldf(lniw, 1 * H_ + col, fp32), lib1 = ldf(lnib, 1 * H_ + col, fp32);
    float lhw1 = ldf(lnhw, 1 * H_ + col, fp32), lhb1 = ldf(lnhb, 1 * H_ + col, fp32);
    float liw2 = ldf(lniw, 2 * H_ + col, fp32), lib2 = ldf(lnib, 2 * H_ + col, fp32);
    float lhw2 = ldf(lnhw, 2 * H_ + col, fp32), lhb2 = ldf(lnhb, 2 * H_ + col, fp32);
    float liw3 = ldf(lniw, 3 * H_ + col, fp32), lib3 = ldf(lnib, 3 * H_ + col, fp32);
    float lhw3 = ldf(lnhw, 3 * H_ + col, fp32), lhb3 = ldf(lnhb, 3 * H_ + col, fp32);
    #pragma unroll
    for (int reg = 0; reg < 4; reg++) {
      int m = quad * 4 + reg;
      float gi = accg[0][reg] + lib0 + lhb0 - mi[reg] * liw0 - mh[reg] * lhw0;
      float gf = accg[1][reg] + lib1 + lhb1 - mi[reg] * liw1 - mh[reg] * lhw1;
      float gg = accg[2][reg] + lib2 + lhb2 - mi[reg] * liw2 - mh[reg] * lhw2;
      float go = accg[3][reg] + lib3 + lhb3 - mi[reg] * liw3 - mh[reg] * lhw3;
      float iv = sigf(gi), fv = sigf(gf), gv = tanh_f(gg), ov = sigf(go);
      float cxv = buf[m][col];
      val[q][reg] = fv * cxv + iv * gv;
      okeep[q][reg] = ov;
    }
  }

  // cy-LN stats
  float s1[4] = {}, s2[4] = {};
  #pragma unroll
  for (int q = 0; q < 4; q++)
    #pragma unroll
    for (int reg = 0; reg < 4; reg++) {
      s1[reg] += val[q][reg];
      s2[reg] += val[q][reg] * val[q][reg];
    }
  #pragma unroll
  for (int d = 1; d < 16; d <<= 1) {
    #pragma unroll
    for (int reg = 0; reg < 4; reg++) {
      s1[reg] += __shfl_xor(s1[reg], d, 64);
      s2[reg] += __shfl_xor(s2[reg], d, 64);
    }
  }
  if (lcol == 0) {
    #pragma unroll
    for (int reg = 0; reg < 4; reg++) {
      wpart[w][quad * 4 + reg][0] = s1[reg];
      wpart[w][quad * 4 + reg][1] = s2[reg];
    }
  }
  __syncthreads();
  if (tid < 16) {
    float t1 = 0.f, t2 = 0.f;
    #pragma unroll
    for (int ww = 0; ww < 16; ww++) { t1 += wpart[ww][tid][0]; t2 += wpart[ww][tid][1]; }
    float mu = t1 * (1.0f / 1024.0f);
    float var = t2 * (1.0f / 1024.0f) - mu * mu;
    mu_s[tid] = mu;
    rs_s[tid] = rsqrtf(var + EPS_);
  }
  __syncthreads();

  // compute cy into buf (MFMA layout), keep hy in regs
  #pragma unroll
  for (int q = 0; q < 4; q++) {
    int col = (w * 4 + q) * 16 + lcol;
    float lw = ldf(lncw, col, fp32), lb = ldf(lncb, col, fp32);
    #pragma unroll
    for (int reg = 0; reg < 4; reg++) {
      int m = quad * 4 + reg;
      float cyv = (val[q][reg] - mu_s[m]) * rs_s[m] * lw + lb;
      buf[m][col] = cyv;
      val[q][reg] = okeep[q][reg] * tanh_f(cyv);   // hy
    }
  }
  __syncthreads();
  // store cy coalesced
  #pragma unroll
  for (int pass = 0; pass < 2; pass++) {
    int e = pass * 8192 + tid * 8;
    int r = e >> 10, c = e & 1023;
    float4 v0 = *(const float4*)&buf[r][c];
    float4 v1 = *(const float4*)&buf[r][c + 4];
    *(float4*)&out[(size_t)B_ * H_ + (b0 + r) * H_ + c] = v0;
    *(float4*)&out[(size_t)B_ * H_ + (b0 + r) * H_ + c + 4] = v1;
  }
  __syncthreads();
  // stage hy into buf
  #pragma unroll
  for (int q = 0; q < 4; q++) {
    int col = (w * 4 + q) * 16 + lcol;
    #pragma unroll
    for (int reg = 0; reg < 4; reg++)
      buf[quad * 4 + reg][col] = val[q][reg];
  }
  __syncthreads();
  // store hy coalesced
  #pragma unroll
  for (int pass = 0; pass < 2; pass++) {
    int e = pass * 8192 + tid * 8;
    int r = e >> 10, c = e & 1023;
    float4 v0 = *(const float4*)&buf[r][c];
    float4 v1 = *(const float4*)&buf[r][c + 4];
    *(float4*)&out[(b0 + r) * H_ + c] = v0;
    *(float4*)&out[(b0 + r) * H_ + c + 4] = v1;
  }
}

// ---------------------------------------------------------------------------
extern "C" void kernel_launch(void* const* d_in, const int* in_sizes, int n_in,
                              void* d_out, int out_size, void* d_ws, size_t ws_size,
                              hipStream_t stream) {
  const void* input_  = d_in[0];
  const void* hx      = d_in[1];
  const void* cx      = d_in[2];
  const void* topic   = d_in[3];
  const void* w_ih_a  = d_in[4];
  const void* w_ih_b  = d_in[5];
  const void* w_ih_c  = d_in[6];
  const void* w_hh_a  = d_in[7];
  const void* w_hh_b  = d_in[8];
  const void* w_hh_c  = d_in[9];
  const void* th_ih_w = d_in[10];
  const void* th_ih_b = d_in[11];
  const void* th_hh_w = d_in[12];
  const void* th_hh_b = d_in[13];
  const void* ln_i_w  = d_in[14];
  const void* ln_i_b  = d_in[15];
  const void* ln_h_w  = d_in[16];
  const void* ln_h_b  = d_in[17];
  const void* ln_c_w  = d_in[18];
  const void* ln_c_b  = d_in[19];

  float* w = (float*)d_ws;
  float* c1    = w;                          // B*F
  float* c2    = c1 + B_ * F_;
  float* g_i   = c2 + B_ * F_;               // F*F
  float* g_h   = g_i + F_ * F_;
  float* cm_i  = g_h + F_ * F_;              // F
  float* cm_h  = cm_i + F_;
  float* mrs_i = cm_h + F_;                  // B
  float* mrs_h = mrs_i + B_;
  ushort_t* xb = (ushort_t*)(mrs_h + B_);    // B*256 bf16 (A-frag order)
  ushort_t* wbf = xb + (size_t)B_ * 256;     // 256*4096 bf16 (B-frag order)

  hipMemsetAsync(g_i, 0, (size_t)(2 * F_ * F_ + 2 * F_) * sizeof(float), stream);

  k_stageA<<<dim3(NG1 + NPREP + NGRAM), dim3(256), 0, stream>>>(
      input_, hx, w_ih_c, w_hh_c, topic,
      th_ih_w, th_hh_w, th_ih_b, th_hh_b, w_ih_b, w_hh_b,
      w_ih_a, w_hh_a, ln_i_w, ln_h_w,
      wbf, cm_i, cm_h, g_i, g_h, c1, c2);
  k_stats2<<<dim3(512), dim3(256), 0, stream>>>(
      c1, c2, g_i, g_h, cm_i, cm_h, mrs_i, mrs_h, xb);
  k_fused<<<dim3(256), dim3(1024), 0, stream>>>(
      xb, wbf, mrs_i, mrs_h,
      ln_i_w, ln_i_b, ln_h_w, ln_h_b, ln_c_w, ln_c_b, cx, (float*)d_out);
}

// Round 2
// 235.193 us; speedup vs baseline: 1.0667x; 1.0594x over previous
//
#include <hip/hip_runtime.h>

typedef unsigned short ushort_t;
typedef __attribute__((ext_vector_type(8))) short bf8_t;   // 8 x bf16 (4 VGPRs)
typedef __attribute__((ext_vector_type(4))) float f4_t;    // MFMA acc

#define B_   4096
#define IN_  1024
#define H_   1024
#define F_   128
#define G4_  4096
#define EPS_ 1e-5f

#define NG1   512   // gemm1 blocks in stageA
#define NPREP 256   // prep blocks
#define NGRAM 128   // gram blocks

__device__ __forceinline__ float us2f(unsigned short s) {
  union { unsigned int u; float f; } v;
  v.u = ((unsigned int)s) << 16;
  return v.f;
}
__device__ __forceinline__ unsigned short f2us(float f) {  // fp32 -> bf16 RNE
  union { float f; unsigned int u; } v;
  v.f = f;
  unsigned int r = (v.u + 0x7fffu + ((v.u >> 16) & 1u)) >> 16;
  return (unsigned short)r;
}
__device__ __forceinline__ float sigf(float x) { return 1.0f / (1.0f + __expf(-x)); }
__device__ __forceinline__ float tanh_f(float x) { return 1.0f - 2.0f / (1.0f + __expf(2.0f * x)); }

// Runtime input-dtype detection (R1/R2 A/B proved fp32; keep as insurance).
__device__ __forceinline__ int detect_fp32(const void* disc) {
  return ((const unsigned int*)disc)[0] == 0x3F800000u;
}
__device__ __forceinline__ float ldf(const void* p, int i, int fp32) {
  return fp32 ? ((const float*)p)[i] : us2f(((const ushort_t*)p)[i]);
}
__device__ __forceinline__ void ld8(const void* p, int idx, float* o, int fp32) {
  if (fp32) {
    const float4* q = (const float4*)((const float*)p + idx);
    float4 v0 = q[0], v1 = q[1];
    o[0]=v0.x; o[1]=v0.y; o[2]=v0.z; o[3]=v0.w;
    o[4]=v1.x; o[5]=v1.y; o[6]=v1.z; o[7]=v1.w;
  } else {
    uint4 v = *(const uint4*)((const ushort_t*)p + idx);
    const ushort_t* pv = (const ushort_t*)&v;
    #pragma unroll
    for (int i = 0; i < 8; i++) o[i] = us2f(pv[i]);
  }
}
// fast fp32x8 -> bf16x8: round-half-up + v_perm_b32 byte pack (1.5 op/elem)
__device__ __forceinline__ bf8_t cvt8p(const float* f) {
  union { bf8_t v; unsigned int u[4]; } r;
  const unsigned int* ui = (const unsigned int*)f;
  #pragma unroll
  for (int i = 0; i < 4; i++) {
    unsigned int lo = ui[2 * i] + 0x8000u;
    unsigned int hi = ui[2 * i + 1] + 0x8000u;
    r.u[i] = __builtin_amdgcn_perm(hi, lo, 0x07060302u);
  }
  return r.v;
}

// ---------------------------------------------------------------------------
// stageA: three independent jobs fused into one launch for co-residency.
// ---------------------------------------------------------------------------
__global__ __launch_bounds__(256, 4) void k_stageA(
    const void* __restrict__ X0, const void* __restrict__ X1,
    const void* __restrict__ Wc0, const void* __restrict__ Wc1,
    const void* __restrict__ topic,
    const void* __restrict__ thw0, const void* __restrict__ thw1,
    const void* __restrict__ thb0, const void* __restrict__ thb1,
    const void* __restrict__ wsb0, const void* __restrict__ wsb1,
    const void* __restrict__ Ai, const void* __restrict__ Ah,
    const void* __restrict__ lnwi, const void* __restrict__ lnwh,
    ushort_t* __restrict__ wb,
    float* __restrict__ cm_i, float* __restrict__ cm_h,
    float* __restrict__ g_i, float* __restrict__ g_h,
    float* __restrict__ C0, float* __restrict__ C1)
{
  __shared__ float smem[32 * 128];   // used by gram branch only
  int bid = blockIdx.x, tid = threadIdx.x;
  int fp32 = detect_fp32(lnwi);

  if (bid < NG1) {
    int rb = bid >> 1, mat = bid & 1;
    const void* X   = mat ? X1 : X0;
    const void* W   = mat ? Wc1 : Wc0;
    const void* thw = mat ? thw1 : thw0;
    const void* thb = mat ? thb1 : thb0;
    const void* wbp = mat ? wsb1 : wsb0;
    float* C = mat ? C1 : C0;
    int lane = tid & 63, w = tid >> 6;
    int quad = lane >> 4, lcol = lane & 15;
    int brow0 = rb * 16;

    f4_t acc[2];
    acc[0] = (f4_t){0.f, 0.f, 0.f, 0.f};
    acc[1] = (f4_t){0.f, 0.f, 0.f, 0.f};

    #pragma unroll 4
    for (int kc = 0; kc < 32; kc++) {
      int kb = kc * 32 + quad * 8;
      float a[8];
      ld8(X, (brow0 + lcol) * IN_ + kb, a, fp32);
      bf8_t af = cvt8p(a);
      #pragma unroll
      for (int t = 0; t < 2; t++) {
        float bt[8];
        ld8(W, ((w * 2 + t) * 16 + lcol) * IN_ + kb, bt, fp32);
        acc[t] = __builtin_amdgcn_mfma_f32_16x16x32_bf16(af, cvt8p(bt), acc[t], 0, 0, 0);
      }
    }

    float thwf[3][3], thbf[3];
    #pragma unroll
    for (int t = 0; t < 3; t++) {
      thbf[t] = ldf(thb, t, fp32);
      #pragma unroll
      for (int t2 = 0; t2 < 3; t2++) thwf[t][t2] = ldf(thw, t * 3 + t2, fp32);
    }
    float tmpv[4][3];
    #pragma unroll
    for (int reg = 0; reg < 4; reg++) {
      int b = brow0 + quad * 4 + reg;
      float tp0 = ldf(topic, b * 3 + 0, fp32);
      float tp1 = ldf(topic, b * 3 + 1, fp32);
      float tp2 = ldf(topic, b * 3 + 2, fp32);
      #pragma unroll
      for (int t = 0; t < 3; t++)
        tmpv[reg][t] = thbf[t] + tp0 * thwf[t][0] + tp1 * thwf[t][1] + tp2 * thwf[t][2];
    }
    #pragma unroll
    for (int t = 0; t < 2; t++) {
      int f = (w * 2 + t) * 16 + lcol;
      float wv0 = ldf(wbp, f * 3 + 0, fp32);
      float wv1 = ldf(wbp, f * 3 + 1, fp32);
      float wv2 = ldf(wbp, f * 3 + 2, fp32);
      #pragma unroll
      for (int reg = 0; reg < 4; reg++) {
        float sc = tmpv[reg][0] * wv0 + tmpv[reg][1] * wv1 + tmpv[reg][2] * wv2;
        C[(brow0 + quad * 4 + reg) * F_ + f] = acc[t][reg] * sc;
      }
    }
  } else if (bid < NG1 + NPREP) {
    int t = bid - NG1;
    #pragma unroll
    for (int i = 0; i < 16; i++) {
      int e = i * 256 + tid;
      int c = e >> 9, l = (e >> 3) & 63, j = e & 7;
      int k = c * 32 + ((l >> 4) << 3) + j;
      int n = t * 16 + (l & 15);
      float v;
      if (k < 128) v = ldf(Ai, n * F_ + k, fp32) * ldf(lnwi, n, fp32);
      else         v = ldf(Ah, n * F_ + (k - 128), fp32) * ldf(lnwh, n, fp32);
      wb[(size_t)t * 4096 + e] = f2us(v);
    }
    const void* A = (tid < 128) ? Ai : Ah;
    float* cm = (tid < 128) ? cm_i : cm_h;
    int f = tid & 127;
    float s = 0.f;
    #pragma unroll
    for (int i = 0; i < 16; i++) s += ldf(A, (t * 16 + i) * F_ + f, fp32);
    atomicAdd(&cm[f], s);
  } else {
    int g = bid - (NG1 + NPREP);
    int fblk = g & 3, mat = (g >> 2) & 1, z = g >> 3;
    const void* A = mat ? Ah : Ai;
    float* G = mat ? g_h : g_i;
    float (*As)[128] = (float(*)[128])smem;
    int f1_0 = fblk * 32;
    int tf2 = tid & 31, tf1 = tid >> 5;
    float acc[4][4] = {};
    int nbase = z * 256;
    for (int n0 = nbase; n0 < nbase + 256; n0 += 32) {
      #pragma unroll
      for (int j = 0; j < 2; j++) {
        int idx = tid + 256 * j;
        int nn = idx >> 4, f8 = (idx & 15) * 8;
        float t[8];
        ld8(A, (n0 + nn) * F_ + f8, t, fp32);
        #pragma unroll
        for (int i = 0; i < 8; i++) As[nn][f8 + i] = t[i];
      }
      __syncthreads();
      #pragma unroll 4
      for (int nn = 0; nn < 32; nn++) {
        float4 a1 = *(const float4*)&As[nn][f1_0 + 4 * tf1];
        float4 a2 = *(const float4*)&As[nn][4 * tf2];
        const float* x1 = (const float*)&a1;
        const float* x2 = (const float*)&a2;
        #pragma unroll
        for (int i = 0; i < 4; i++)
          #pragma unroll
          for (int j = 0; j < 4; j++) acc[i][j] += x1[i] * x2[j];
      }
      __syncthreads();
    }
    #pragma unroll
    for (int i = 0; i < 4; i++)
      #pragma unroll
      for (int j = 0; j < 4; j++)
        atomicAdd(&G[(f1_0 + 4 * tf1 + i) * F_ + 4 * tf2 + j], acc[i][j]);
  }
}

// ---------------------------------------------------------------------------
// stats2: per-row LN stats via quadratic form
// ---------------------------------------------------------------------------
__global__ __launch_bounds__(256, 4) void k_stats2(
    const float* __restrict__ C0, const float* __restrict__ C1,
    const float* __restrict__ g_i, const float* __restrict__ g_h,
    const float* __restrict__ cm_i, const float* __restrict__ cm_h,
    float* __restrict__ mrs_i, float* __restrict__ mrs_h,
    ushort_t* __restrict__ xb)
{
  int bid = blockIdx.x;
  int rb = bid >> 1, mat = bid & 1;
  const float* C  = mat ? C1 : C0;
  const float* G  = mat ? g_h : g_i;
  const float* cm = mat ? cm_h : cm_i;
  float* mrs = mat ? mrs_h : mrs_i;
  int kbase = mat ? 128 : 0;

  int tid = threadIdx.x;
  int lane = tid & 63, w = tid >> 6;
  int quad = lane >> 4, lcol = lane & 15;
  int b0 = rb * 16;

  __shared__ float p1part[4][16];
  __shared__ float p2s[16];
  __shared__ float rs_s[16];

  bf8_t af[4];
  float p2p = 0.f;
  #pragma unroll
  for (int kc = 0; kc < 4; kc++) {
    int kb = kc * 32 + quad * 8;
    const float4* q = (const float4*)(C + (b0 + lcol) * F_ + kb);
    float4 v0 = q[0], v1 = q[1];
    float a[8] = {v0.x, v0.y, v0.z, v0.w, v1.x, v1.y, v1.z, v1.w};
    af[kc] = cvt8p(a);
    if (w == 0) {
      #pragma unroll
      for (int j = 0; j < 8; j++) p2p += a[j] * cm[kb + j];
    }
  }

  float p1p[4] = {0.f, 0.f, 0.f, 0.f};
  #pragma unroll
  for (int t = 0; t < 2; t++) {
    int colf = (w * 2 + t) * 16 + lcol;
    f4_t acc = {0.f, 0.f, 0.f, 0.f};
    #pragma unroll
    for (int kc = 0; kc < 4; kc++) {
      const float4* qg = (const float4*)(G + colf * F_ + kc * 32 + quad * 8);
      float4 w0 = qg[0], w1 = qg[1];
      float bt[8] = {w0.x, w0.y, w0.z, w0.w, w1.x, w1.y, w1.z, w1.w};
      acc = __builtin_amdgcn_mfma_f32_16x16x32_bf16(af[kc], cvt8p(bt), acc, 0, 0, 0);
    }
    #pragma unroll
    for (int reg = 0; reg < 4; reg++)
      p1p[reg] += acc[reg] * C[(b0 + quad * 4 + reg) * F_ + colf];
  }
  #pragma unroll
  for (int d = 1; d < 16; d <<= 1)
    #pragma unroll
    for (int reg = 0; reg < 4; reg++)
      p1p[reg] += __shfl_xor(p1p[reg], d, 64);
  if (lcol == 0) {
    #pragma unroll
    for (int reg = 0; reg < 4; reg++)
      p1part[w][quad * 4 + reg] = p1p[reg];
  }
  if (w == 0) {
    p2p += __shfl_xor(p2p, 16, 64);
    p2p += __shfl_xor(p2p, 32, 64);
    if (quad == 0) p2s[lcol] = p2p;
  }
  __syncthreads();
  if (tid < 16) {
    float p1 = p1part[0][tid] + p1part[1][tid] + p1part[2][tid] + p1part[3][tid];
    float E2 = p1 * (1.0f / 4096.0f);
    float mu = p2s[tid] * (1.0f / 4096.0f);
    float var = E2 - mu * mu;
    float rs = rsqrtf(var + EPS_);
    rs_s[tid] = rs;
    mrs[b0 + tid] = mu * rs;
  }
  __syncthreads();
  int f = tid & 127, half = tid >> 7;
  ushort_t* xbb = xb + (size_t)rb * 4096;
  int k = kbase + f;
  int c = k >> 5, lq = (k >> 3) & 3, j = k & 7;
  #pragma unroll
  for (int i = 0; i < 8; i++) {
    int r2 = half * 8 + i;
    int lfrag = r2 | (lq << 4);
    xbb[c * 512 + lfrag * 8 + j] = f2us(C[(b0 + r2) * F_ + f] * rs_s[r2]);
  }
}

// ---------------------------------------------------------------------------
// K6 v5: register-pressure restructure. R7's launch_bounds attempt was a
// no-op (VGPR stayed 64, spill traffic stayed: WRITE 93MB vs 32 ideal).
// Changes vs v4:
//  - val[4][4] eliminated: c = f*cx+i*g written IN PLACE over cx in buf
//    (same thread owns the element; race-free). LN sums accumulate in 8 regs.
//  - okeep[4][4] -> obuf LDS array (o stored, applied after LN).
//  - af[8] reloaded per q (xb is 8KB/block, L1-resident) so it is not live
//    across the gate-math phase.
//  - LDS = 133.8KB forces occupancy calc to 1 blk/CU (grid=256=1/CU anyway)
//    -> backend VGPR budget 128 by its own arithmetic.
//  - hy written into obuf -> one restage pass + 2 barriers removed; cy and
//    hy both stored coalesced at the end.
// ---------------------------------------------------------------------------
__global__ __launch_bounds__(1024, 4) void k_fused(
    const ushort_t* __restrict__ xb, const ushort_t* __restrict__ wb,
    const float* __restrict__ mrs_i, const float* __restrict__ mrs_h,
    const void* __restrict__ lniw, const void* __restrict__ lnib,
    const void* __restrict__ lnhw, const void* __restrict__ lnhb,
    const void* __restrict__ lncw, const void* __restrict__ lncb,
    const void* __restrict__ cx, float* __restrict__ out)
{
  __shared__ float buf[16][1028];    // cx -> c(pre-LN) -> cy
  __shared__ float obuf[16][1028];   // o(sigmoid) -> hy
  __shared__ float wpart[16][16][2];
  __shared__ float mu_s[16], rs_s[16];
  int tid = threadIdx.x;
  int lane = tid & 63, w = tid >> 6;
  int quad = lane >> 4, lcol = lane & 15;
  int b0 = blockIdx.x * 16;
  int fp32 = detect_fp32(lniw);

  // ---- stage cx into LDS, fully coalesced (2 passes x 8 floats/thread) ----
  #pragma unroll
  for (int pass = 0; pass < 2; pass++) {
    int e = pass * 8192 + tid * 8;
    int r = e >> 10, c = e & 1023;
    float t[8];
    ld8(cx, (b0 + r) * H_ + c, t, fp32);
    *(float4*)&buf[r][c] = *(float4*)&t[0];
    *(float4*)&buf[r][c + 4] = *(float4*)&t[4];
  }

  const ushort_t* xblk = xb + (size_t)blockIdx.x * 4096;

  float mi[4], mh[4];
  #pragma unroll
  for (int reg = 0; reg < 4; reg++) {
    mi[reg] = mrs_i[b0 + quad * 4 + reg];
    mh[reg] = mrs_h[b0 + quad * 4 + reg];
  }
  __syncthreads();

  float s1[4] = {0.f, 0.f, 0.f, 0.f}, s2[4] = {0.f, 0.f, 0.f, 0.f};

  #pragma unroll
  for (int q = 0; q < 4; q++) {
    int cg = w * 4 + q;
    int col = cg * 16 + lcol;
    // A-fragments reloaded per q: keeps them dead during the gate-math phase
    bf8_t af[8];
    #pragma unroll
    for (int c = 0; c < 8; c++)
      af[c] = *(const bf8_t*)(xblk + c * 512 + lane * 8);
    f4_t accg[4];
    #pragma unroll
    for (int g = 0; g < 4; g++) {
      f4_t acc = {0.f, 0.f, 0.f, 0.f};
      int t = g * 64 + cg;
      const ushort_t* wt = wb + (size_t)t * 4096 + lane * 8;
      #pragma unroll
      for (int c = 0; c < 8; c++) {
        bf8_t bf = *(const bf8_t*)(wt + c * 512);
        acc = __builtin_amdgcn_mfma_f32_16x16x32_bf16(af[c], bf, acc, 0, 0, 0);
      }
      accg[g] = acc;
    }
    float liw0 = ldf(lniw, 0 * H_ + col, fp32), lib0 = ldf(lnib, 0 * H_ + col, fp32);
    float lhw0 = ldf(lnhw, 0 * H_ + col, fp32), lhb0 = ldf(lnhb, 0 * H_ + col, fp32);
    float liw1 = ldf(lniw, 1 * H_ + col, fp32), lib1 = ldf(lnib, 1 * H_ + col, fp32);
    float lhw1 = ldf(lnhw, 1 * H_ + col, fp32), lhb1 = ldf(lnhb, 1 * H_ + col, fp32);
    float liw2 = ldf(lniw, 2 * H_ + col, fp32), lib2 = ldf(lnib, 2 * H_ + col, fp32);
    float lhw2 = ldf(lnhw, 2 * H_ + col, fp32), lhb2 = ldf(lnhb, 2 * H_ + col, fp32);
    float liw3 = ldf(lniw, 3 * H_ + col, fp32), lib3 = ldf(lnib, 3 * H_ + col, fp32);
    float lhw3 = ldf(lnhw, 3 * H_ + col, fp32), lhb3 = ldf(lnhb, 3 * H_ + col, fp32);
    #pragma unroll
    for (int reg = 0; reg < 4; reg++) {
      int m = quad * 4 + reg;
      float gi = accg[0][reg] + lib0 + lhb0 - mi[reg] * liw0 - mh[reg] * lhw0;
      float gf = accg[1][reg] + lib1 + lhb1 - mi[reg] * liw1 - mh[reg] * lhw1;
      float gg = accg[2][reg] + lib2 + lhb2 - mi[reg] * liw2 - mh[reg] * lhw2;
      float go = accg[3][reg] + lib3 + lhb3 - mi[reg] * liw3 - mh[reg] * lhw3;
      float iv = sigf(gi), fv = sigf(gf), gv = tanh_f(gg), ov = sigf(go);
      float cxv = buf[m][col];
      float cval = fv * cxv + iv * gv;
      buf[m][col] = cval;          // c pre-LN, in place over cx
      obuf[m][col] = ov;           // o-gate, applied after LN
      s1[reg] += cval;
      s2[reg] += cval * cval;
    }
  }

  // cy-LN stats reduce
  #pragma unroll
  for (int d = 1; d < 16; d <<= 1) {
    #pragma unroll
    for (int reg = 0; reg < 4; reg++) {
      s1[reg] += __shfl_xor(s1[reg], d, 64);
      s2[reg] += __shfl_xor(s2[reg], d, 64);
    }
  }
  if (lcol == 0) {
    #pragma unroll
    for (int reg = 0; reg < 4; reg++) {
      wpart[w][quad * 4 + reg][0] = s1[reg];
      wpart[w][quad * 4 + reg][1] = s2[reg];
    }
  }
  __syncthreads();
  if (tid < 16) {
    float t1 = 0.f, t2 = 0.f;
    #pragma unroll
    for (int ww = 0; ww < 16; ww++) { t1 += wpart[ww][tid][0]; t2 += wpart[ww][tid][1]; }
    float mu = t1 * (1.0f / 1024.0f);
    float var = t2 * (1.0f / 1024.0f) - mu * mu;
    mu_s[tid] = mu;
    rs_s[tid] = rsqrtf(var + EPS_);
  }
  __syncthreads();

  // cy + hy, both into LDS (each thread owns its (m,col) elements)
  #pragma unroll
  for (int q = 0; q < 4; q++) {
    int col = (w * 4 + q) * 16 + lcol;
    float lw = ldf(lncw, col, fp32), lb = ldf(lncb, col, fp32);
    #pragma unroll
    for (int reg = 0; reg < 4; reg++) {
      int m = quad * 4 + reg;
      float cyv = (buf[m][col] - mu_s[m]) * rs_s[m] * lw + lb;
      buf[m][col] = cyv;
      obuf[m][col] = obuf[m][col] * tanh_f(cyv);   // hy
    }
  }
  __syncthreads();
  // store cy (from buf) and hy (from obuf), coalesced
  #pragma unroll
  for (int pass = 0; pass < 2; pass++) {
    int e = pass * 8192 + tid * 8;
    int r = e >> 10, c = e & 1023;
    float4 c0 = *(const float4*)&buf[r][c];
    float4 c1v = *(const float4*)&buf[r][c + 4];
    *(float4*)&out[(size_t)B_ * H_ + (b0 + r) * H_ + c] = c0;
    *(float4*)&out[(size_t)B_ * H_ + (b0 + r) * H_ + c + 4] = c1v;
    float4 h0 = *(const float4*)&obuf[r][c];
    float4 h1 = *(const float4*)&obuf[r][c + 4];
    *(float4*)&out[(b0 + r) * H_ + c] = h0;
    *(float4*)&out[(b0 + r) * H_ + c + 4] = h1;
  }
}

// ---------------------------------------------------------------------------
extern "C" void kernel_launch(void* const* d_in, const int* in_sizes, int n_in,
                              void* d_out, int out_size, void* d_ws, size_t ws_size,
                              hipStream_t stream) {
  const void* input_  = d_in[0];
  const void* hx      = d_in[1];
  const void* cx      = d_in[2];
  const void* topic   = d_in[3];
  const void* w_ih_a  = d_in[4];
  const void* w_ih_b  = d_in[5];
  const void* w_ih_c  = d_in[6];
  const void* w_hh_a  = d_in[7];
  const void* w_hh_b  = d_in[8];
  const void* w_hh_c  = d_in[9];
  const void* th_ih_w = d_in[10];
  const void* th_ih_b = d_in[11];
  const void* th_hh_w = d_in[12];
  const void* th_hh_b = d_in[13];
  const void* ln_i_w  = d_in[14];
  const void* ln_i_b  = d_in[15];
  const void* ln_h_w  = d_in[16];
  const void* ln_h_b  = d_in[17];
  const void* ln_c_w  = d_in[18];
  const void* ln_c_b  = d_in[19];

  float* w = (float*)d_ws;
  float* c1    = w;                          // B*F
  float* c2    = c1 + B_ * F_;
  float* g_i   = c2 + B_ * F_;               // F*F
  float* g_h   = g_i + F_ * F_;
  float* cm_i  = g_h + F_ * F_;              // F
  float* cm_h  = cm_i + F_;
  float* mrs_i = cm_h + F_;                  // B
  float* mrs_h = mrs_i + B_;
  ushort_t* xb = (ushort_t*)(mrs_h + B_);    // B*256 bf16 (A-frag order)
  ushort_t* wbf = xb + (size_t)B_ * 256;     // 256*4096 bf16 (B-frag order)

  hipMemsetAsync(g_i, 0, (size_t)(2 * F_ * F_ + 2 * F_) * sizeof(float), stream);

  k_stageA<<<dim3(NG1 + NPREP + NGRAM), dim3(256), 0, stream>>>(
      input_, hx, w_ih_c, w_hh_c, topic,
      th_ih_w, th_hh_w, th_ih_b, th_hh_b, w_ih_b, w_hh_b,
      w_ih_a, w_hh_a, ln_i_w, ln_h_w,
      wbf, cm_i, cm_h, g_i, g_h, c1, c2);
  k_stats2<<<dim3(512), dim3(256), 0, stream>>>(
      c1, c2, g_i, g_h, cm_i, cm_h, mrs_i, mrs_h, xb);
  k_fused<<<dim3(256), dim3(1024), 0, stream>>>(
      xb, wbf, mrs_i, mrs_h,
      ln_i_w, ln_i_b, ln_h_w, ln_h_b, ln_c_w, ln_c_b, cx, (float*)d_out);
}

// Round 3
// 226.319 us; speedup vs baseline: 1.1086x; 1.0392x over previous
//
#include <hip/hip_runtime.h>

typedef unsigned short ushort_t;
typedef __attribute__((ext_vector_type(8))) short bf8_t;   // 8 x bf16 (4 VGPRs)
typedef __attribute__((ext_vector_type(4))) float f4_t;    // MFMA acc

#define B_   4096
#define IN_  1024
#define H_   1024
#define F_   128
#define G4_  4096
#define EPS_ 1e-5f

#define NG1   512   // gemm1 blocks in stageA
#define NPREP 256   // prep blocks
#define NGRAM 128   // gram blocks

__device__ __forceinline__ float us2f(unsigned short s) {
  union { unsigned int u; float f; } v;
  v.u = ((unsigned int)s) << 16;
  return v.f;
}
__device__ __forceinline__ unsigned short f2us(float f) {  // fp32 -> bf16 RNE
  union { float f; unsigned int u; } v;
  v.f = f;
  unsigned int r = (v.u + 0x7fffu + ((v.u >> 16) & 1u)) >> 16;
  return (unsigned short)r;
}
__device__ __forceinline__ float sigf(float x) { return 1.0f / (1.0f + __expf(-x)); }
__device__ __forceinline__ float tanh_f(float x) { return 1.0f - 2.0f / (1.0f + __expf(2.0f * x)); }

// Runtime input-dtype detection (R1/R2 A/B proved fp32; keep as insurance).
__device__ __forceinline__ int detect_fp32(const void* disc) {
  return ((const unsigned int*)disc)[0] == 0x3F800000u;
}
__device__ __forceinline__ float ldf(const void* p, int i, int fp32) {
  return fp32 ? ((const float*)p)[i] : us2f(((const ushort_t*)p)[i]);
}
__device__ __forceinline__ void ld8(const void* p, int idx, float* o, int fp32) {
  if (fp32) {
    const float4* q = (const float4*)((const float*)p + idx);
    float4 v0 = q[0], v1 = q[1];
    o[0]=v0.x; o[1]=v0.y; o[2]=v0.z; o[3]=v0.w;
    o[4]=v1.x; o[5]=v1.y; o[6]=v1.z; o[7]=v1.w;
  } else {
    uint4 v = *(const uint4*)((const ushort_t*)p + idx);
    const ushort_t* pv = (const ushort_t*)&v;
    #pragma unroll
    for (int i = 0; i < 8; i++) o[i] = us2f(pv[i]);
  }
}
// fast fp32x8 -> bf16x8: round-half-up + v_perm_b32 byte pack (1.5 op/elem)
__device__ __forceinline__ bf8_t cvt8p(const float* f) {
  union { bf8_t v; unsigned int u[4]; } r;
  const unsigned int* ui = (const unsigned int*)f;
  #pragma unroll
  for (int i = 0; i < 4; i++) {
    unsigned int lo = ui[2 * i] + 0x8000u;
    unsigned int hi = ui[2 * i + 1] + 0x8000u;
    r.u[i] = __builtin_amdgcn_perm(hi, lo, 0x07060302u);
  }
  return r.v;
}

// ---------------------------------------------------------------------------
// stageA: three independent jobs fused into one launch for co-residency.
// ---------------------------------------------------------------------------
__global__ __launch_bounds__(256, 4) void k_stageA(
    const void* __restrict__ X0, const void* __restrict__ X1,
    const void* __restrict__ Wc0, const void* __restrict__ Wc1,
    const void* __restrict__ topic,
    const void* __restrict__ thw0, const void* __restrict__ thw1,
    const void* __restrict__ thb0, const void* __restrict__ thb1,
    const void* __restrict__ wsb0, const void* __restrict__ wsb1,
    const void* __restrict__ Ai, const void* __restrict__ Ah,
    const void* __restrict__ lnwi, const void* __restrict__ lnwh,
    ushort_t* __restrict__ wb,
    float* __restrict__ cm_i, float* __restrict__ cm_h,
    float* __restrict__ g_i, float* __restrict__ g_h,
    float* __restrict__ C0, float* __restrict__ C1)
{
  __shared__ float smem[32 * 128];   // used by gram branch only
  int bid = blockIdx.x, tid = threadIdx.x;
  int fp32 = detect_fp32(lnwi);

  if (bid < NG1) {
    int rb = bid >> 1, mat = bid & 1;
    const void* X   = mat ? X1 : X0;
    const void* W   = mat ? Wc1 : Wc0;
    const void* thw = mat ? thw1 : thw0;
    const void* thb = mat ? thb1 : thb0;
    const void* wbp = mat ? wsb1 : wsb0;
    float* C = mat ? C1 : C0;
    int lane = tid & 63, w = tid >> 6;
    int quad = lane >> 4, lcol = lane & 15;
    int brow0 = rb * 16;

    f4_t acc[2];
    acc[0] = (f4_t){0.f, 0.f, 0.f, 0.f};
    acc[1] = (f4_t){0.f, 0.f, 0.f, 0.f};

    #pragma unroll 4
    for (int kc = 0; kc < 32; kc++) {
      int kb = kc * 32 + quad * 8;
      float a[8];
      ld8(X, (brow0 + lcol) * IN_ + kb, a, fp32);
      bf8_t af = cvt8p(a);
      #pragma unroll
      for (int t = 0; t < 2; t++) {
        float bt[8];
        ld8(W, ((w * 2 + t) * 16 + lcol) * IN_ + kb, bt, fp32);
        acc[t] = __builtin_amdgcn_mfma_f32_16x16x32_bf16(af, cvt8p(bt), acc[t], 0, 0, 0);
      }
    }

    float thwf[3][3], thbf[3];
    #pragma unroll
    for (int t = 0; t < 3; t++) {
      thbf[t] = ldf(thb, t, fp32);
      #pragma unroll
      for (int t2 = 0; t2 < 3; t2++) thwf[t][t2] = ldf(thw, t * 3 + t2, fp32);
    }
    float tmpv[4][3];
    #pragma unroll
    for (int reg = 0; reg < 4; reg++) {
      int b = brow0 + quad * 4 + reg;
      float tp0 = ldf(topic, b * 3 + 0, fp32);
      float tp1 = ldf(topic, b * 3 + 1, fp32);
      float tp2 = ldf(topic, b * 3 + 2, fp32);
      #pragma unroll
      for (int t = 0; t < 3; t++)
        tmpv[reg][t] = thbf[t] + tp0 * thwf[t][0] + tp1 * thwf[t][1] + tp2 * thwf[t][2];
    }
    #pragma unroll
    for (int t = 0; t < 2; t++) {
      int f = (w * 2 + t) * 16 + lcol;
      float wv0 = ldf(wbp, f * 3 + 0, fp32);
      float wv1 = ldf(wbp, f * 3 + 1, fp32);
      float wv2 = ldf(wbp, f * 3 + 2, fp32);
      #pragma unroll
      for (int reg = 0; reg < 4; reg++) {
        float sc = tmpv[reg][0] * wv0 + tmpv[reg][1] * wv1 + tmpv[reg][2] * wv2;
        C[(brow0 + quad * 4 + reg) * F_ + f] = acc[t][reg] * sc;
      }
    }
  } else if (bid < NG1 + NPREP) {
    int t = bid - NG1;
    #pragma unroll
    for (int i = 0; i < 16; i++) {
      int e = i * 256 + tid;
      int c = e >> 9, l = (e >> 3) & 63, j = e & 7;
      int k = c * 32 + ((l >> 4) << 3) + j;
      int n = t * 16 + (l & 15);
      float v;
      if (k < 128) v = ldf(Ai, n * F_ + k, fp32) * ldf(lnwi, n, fp32);
      else         v = ldf(Ah, n * F_ + (k - 128), fp32) * ldf(lnwh, n, fp32);
      wb[(size_t)t * 4096 + e] = f2us(v);
    }
    const void* A = (tid < 128) ? Ai : Ah;
    float* cm = (tid < 128) ? cm_i : cm_h;
    int f = tid & 127;
    float s = 0.f;
    #pragma unroll
    for (int i = 0; i < 16; i++) s += ldf(A, (t * 16 + i) * F_ + f, fp32);
    atomicAdd(&cm[f], s);
  } else {
    int g = bid - (NG1 + NPREP);
    int fblk = g & 3, mat = (g >> 2) & 1, z = g >> 3;
    const void* A = mat ? Ah : Ai;
    float* G = mat ? g_h : g_i;
    float (*As)[128] = (float(*)[128])smem;
    int f1_0 = fblk * 32;
    int tf2 = tid & 31, tf1 = tid >> 5;
    float acc[4][4] = {};
    int nbase = z * 256;
    for (int n0 = nbase; n0 < nbase + 256; n0 += 32) {
      #pragma unroll
      for (int j = 0; j < 2; j++) {
        int idx = tid + 256 * j;
        int nn = idx >> 4, f8 = (idx & 15) * 8;
        float t[8];
        ld8(A, (n0 + nn) * F_ + f8, t, fp32);
        #pragma unroll
        for (int i = 0; i < 8; i++) As[nn][f8 + i] = t[i];
      }
      __syncthreads();
      #pragma unroll 4
      for (int nn = 0; nn < 32; nn++) {
        float4 a1 = *(const float4*)&As[nn][f1_0 + 4 * tf1];
        float4 a2 = *(const float4*)&As[nn][4 * tf2];
        const float* x1 = (const float*)&a1;
        const float* x2 = (const float*)&a2;
        #pragma unroll
        for (int i = 0; i < 4; i++)
          #pragma unroll
          for (int j = 0; j < 4; j++) acc[i][j] += x1[i] * x2[j];
      }
      __syncthreads();
    }
    #pragma unroll
    for (int i = 0; i < 4; i++)
      #pragma unroll
      for (int j = 0; j < 4; j++)
        atomicAdd(&G[(f1_0 + 4 * tf1 + i) * F_ + 4 * tf2 + j], acc[i][j]);
  }
}

// ---------------------------------------------------------------------------
// stats2: per-row LN stats via quadratic form
// ---------------------------------------------------------------------------
__global__ __launch_bounds__(256, 4) void k_stats2(
    const float* __restrict__ C0, const float* __restrict__ C1,
    const float* __restrict__ g_i, const float* __restrict__ g_h,
    const float* __restrict__ cm_i, const float* __restrict__ cm_h,
    float* __restrict__ mrs_i, float* __restrict__ mrs_h,
    ushort_t* __restrict__ xb)
{
  int bid = blockIdx.x;
  int rb = bid >> 1, mat = bid & 1;
  const float* C  = mat ? C1 : C0;
  const float* G  = mat ? g_h : g_i;
  const float* cm = mat ? cm_h : cm_i;
  float* mrs = mat ? mrs_h : mrs_i;
  int kbase = mat ? 128 : 0;

  int tid = threadIdx.x;
  int lane = tid & 63, w = tid >> 6;
  int quad = lane >> 4, lcol = lane & 15;
  int b0 = rb * 16;

  __shared__ float p1part[4][16];
  __shared__ float p2s[16];
  __shared__ float rs_s[16];

  bf8_t af[4];
  float p2p = 0.f;
  #pragma unroll
  for (int kc = 0; kc < 4; kc++) {
    int kb = kc * 32 + quad * 8;
    const float4* q = (const float4*)(C + (b0 + lcol) * F_ + kb);
    float4 v0 = q[0], v1 = q[1];
    float a[8] = {v0.x, v0.y, v0.z, v0.w, v1.x, v1.y, v1.z, v1.w};
    af[kc] = cvt8p(a);
    if (w == 0) {
      #pragma unroll
      for (int j = 0; j < 8; j++) p2p += a[j] * cm[kb + j];
    }
  }

  float p1p[4] = {0.f, 0.f, 0.f, 0.f};
  #pragma unroll
  for (int t = 0; t < 2; t++) {
    int colf = (w * 2 + t) * 16 + lcol;
    f4_t acc = {0.f, 0.f, 0.f, 0.f};
    #pragma unroll
    for (int kc = 0; kc < 4; kc++) {
      const float4* qg = (const float4*)(G + colf * F_ + kc * 32 + quad * 8);
      float4 w0 = qg[0], w1 = qg[1];
      float bt[8] = {w0.x, w0.y, w0.z, w0.w, w1.x, w1.y, w1.z, w1.w};
      acc = __builtin_amdgcn_mfma_f32_16x16x32_bf16(af[kc], cvt8p(bt), acc, 0, 0, 0);
    }
    #pragma unroll
    for (int reg = 0; reg < 4; reg++)
      p1p[reg] += acc[reg] * C[(b0 + quad * 4 + reg) * F_ + colf];
  }
  #pragma unroll
  for (int d = 1; d < 16; d <<= 1)
    #pragma unroll
    for (int reg = 0; reg < 4; reg++)
      p1p[reg] += __shfl_xor(p1p[reg], d, 64);
  if (lcol == 0) {
    #pragma unroll
    for (int reg = 0; reg < 4; reg++)
      p1part[w][quad * 4 + reg] = p1p[reg];
  }
  if (w == 0) {
    p2p += __shfl_xor(p2p, 16, 64);
    p2p += __shfl_xor(p2p, 32, 64);
    if (quad == 0) p2s[lcol] = p2p;
  }
  __syncthreads();
  if (tid < 16) {
    float p1 = p1part[0][tid] + p1part[1][tid] + p1part[2][tid] + p1part[3][tid];
    float E2 = p1 * (1.0f / 4096.0f);
    float mu = p2s[tid] * (1.0f / 4096.0f);
    float var = E2 - mu * mu;
    float rs = rsqrtf(var + EPS_);
    rs_s[tid] = rs;
    mrs[b0 + tid] = mu * rs;
  }
  __syncthreads();
  int f = tid & 127, half = tid >> 7;
  ushort_t* xbb = xb + (size_t)rb * 4096;
  int k = kbase + f;
  int c = k >> 5, lq = (k >> 3) & 3, j = k & 7;
  #pragma unroll
  for (int i = 0; i < 8; i++) {
    int r2 = half * 8 + i;
    int lfrag = r2 | (lq << 4);
    xbb[c * 512 + lfrag * 8 + j] = f2us(C[(b0 + r2) * F_ + f] * rs_s[r2]);
  }
}

// ---------------------------------------------------------------------------
// K6 v6: flat phase structure. R2 proved traffic is ideal (WRITE=32MB exact)
// yet dur unchanged -> latency-bound phase serialization (1 block/CU, 16
// waves lockstep through 6 barriers). v6 removes phases:
//  - no cx staging: cx loaded directly in gate math (lanes 0-15 read 16
//    consecutive floats = full 64B granules; issued at top of q, hidden
//    under the 32 MFMAs).
//  - no store staging: cy/hy stored direct from regs (same granule-aligned
//    pattern; R2 proved old write-amp was spill, not the store pattern).
//  - xb staged to LDS (8KB); af streamed per-c via ds_read_b128 in a
//    c-outer/g-inner loop: af read once per c, MFMAs rotate over 4 accs
//    (no dependency chain), 32 VGPRs freed -> deeper load pipelining at
//    the 64-reg cap with zero spill (peak live ~56).
//  - barriers 6 -> 3.
// Falsifier: if dur stays ~72-75, per-CU concurrency is the limit -> next
// round split columns into a 2-kernel pipeline for 32 waves/CU.
// ---------------------------------------------------------------------------
__global__ __launch_bounds__(1024) void k_fused(
    const ushort_t* __restrict__ xb, const ushort_t* __restrict__ wb,
    const float* __restrict__ mrs_i, const float* __restrict__ mrs_h,
    const void* __restrict__ lniw, const void* __restrict__ lnib,
    const void* __restrict__ lnhw, const void* __restrict__ lnhb,
    const void* __restrict__ lncw, const void* __restrict__ lncb,
    const void* __restrict__ cx, float* __restrict__ out)
{
  __shared__ float buf[16][1028];    // c pre-LN (written by owning thread)
  __shared__ float obuf[16][1028];   // o-gate
  __shared__ ushort_t xs[4096];      // xb tile (A-fragments)
  __shared__ float wpart[16][16][2];
  __shared__ float mu_s[16], rs_s[16];
  int tid = threadIdx.x;
  int lane = tid & 63, w = tid >> 6;
  int quad = lane >> 4, lcol = lane & 15;
  int b0 = blockIdx.x * 16;
  int fp32 = detect_fp32(lniw);

  // stage xb tile (8KB) into LDS: one 8B copy per thread
  ((unsigned long long*)xs)[tid] =
      ((const unsigned long long*)(xb + (size_t)blockIdx.x * 4096))[tid];

  float mi[4], mh[4];
  #pragma unroll
  for (int reg = 0; reg < 4; reg++) {
    mi[reg] = mrs_i[b0 + quad * 4 + reg];
    mh[reg] = mrs_h[b0 + quad * 4 + reg];
  }
  __syncthreads();

  float s1[4] = {0.f, 0.f, 0.f, 0.f}, s2[4] = {0.f, 0.f, 0.f, 0.f};

  #pragma unroll
  for (int q = 0; q < 4; q++) {
    int cg = w * 4 + q;
    int col = cg * 16 + lcol;
    // issue cx loads early: latency hides under the MFMA block
    float cxv[4];
    #pragma unroll
    for (int reg = 0; reg < 4; reg++)
      cxv[reg] = ldf(cx, (size_t)(b0 + quad * 4 + reg) * H_ + col, fp32);

    f4_t accg[4];
    #pragma unroll
    for (int g = 0; g < 4; g++) accg[g] = (f4_t){0.f, 0.f, 0.f, 0.f};
    // c-outer / g-inner: af from LDS once per c; 4 MFMAs rotate over accs
    #pragma unroll
    for (int c = 0; c < 8; c++) {
      bf8_t af = *(const bf8_t*)&xs[c * 512 + lane * 8];
      #pragma unroll
      for (int g = 0; g < 4; g++) {
        bf8_t bf = *(const bf8_t*)(wb + (size_t)(g * 64 + cg) * 4096 + c * 512 + lane * 8);
        accg[g] = __builtin_amdgcn_mfma_f32_16x16x32_bf16(af, bf, accg[g], 0, 0, 0);
      }
    }
    float liw0 = ldf(lniw, 0 * H_ + col, fp32), lib0 = ldf(lnib, 0 * H_ + col, fp32);
    float lhw0 = ldf(lnhw, 0 * H_ + col, fp32), lhb0 = ldf(lnhb, 0 * H_ + col, fp32);
    float liw1 = ldf(lniw, 1 * H_ + col, fp32), lib1 = ldf(lnib, 1 * H_ + col, fp32);
    float lhw1 = ldf(lnhw, 1 * H_ + col, fp32), lhb1 = ldf(lnhb, 1 * H_ + col, fp32);
    float liw2 = ldf(lniw, 2 * H_ + col, fp32), lib2 = ldf(lnib, 2 * H_ + col, fp32);
    float lhw2 = ldf(lnhw, 2 * H_ + col, fp32), lhb2 = ldf(lnhb, 2 * H_ + col, fp32);
    float liw3 = ldf(lniw, 3 * H_ + col, fp32), lib3 = ldf(lnib, 3 * H_ + col, fp32);
    float lhw3 = ldf(lnhw, 3 * H_ + col, fp32), lhb3 = ldf(lnhb, 3 * H_ + col, fp32);
    #pragma unroll
    for (int reg = 0; reg < 4; reg++) {
      int m = quad * 4 + reg;
      float gi = accg[0][reg] + lib0 + lhb0 - mi[reg] * liw0 - mh[reg] * lhw0;
      float gf = accg[1][reg] + lib1 + lhb1 - mi[reg] * liw1 - mh[reg] * lhw1;
      float gg = accg[2][reg] + lib2 + lhb2 - mi[reg] * liw2 - mh[reg] * lhw2;
      float go = accg[3][reg] + lib3 + lhb3 - mi[reg] * liw3 - mh[reg] * lhw3;
      float iv = sigf(gi), fv = sigf(gf), gv = tanh_f(gg), ov = sigf(go);
      float cval = fv * cxv[reg] + iv * gv;
      buf[m][col] = cval;
      obuf[m][col] = ov;
      s1[reg] += cval;
      s2[reg] += cval * cval;
    }
  }

  // cy-LN stats reduce
  #pragma unroll
  for (int d = 1; d < 16; d <<= 1) {
    #pragma unroll
    for (int reg = 0; reg < 4; reg++) {
      s1[reg] += __shfl_xor(s1[reg], d, 64);
      s2[reg] += __shfl_xor(s2[reg], d, 64);
    }
  }
  if (lcol == 0) {
    #pragma unroll
    for (int reg = 0; reg < 4; reg++) {
      wpart[w][quad * 4 + reg][0] = s1[reg];
      wpart[w][quad * 4 + reg][1] = s2[reg];
    }
  }
  __syncthreads();
  if (tid < 16) {
    float t1 = 0.f, t2 = 0.f;
    #pragma unroll
    for (int ww = 0; ww < 16; ww++) { t1 += wpart[ww][tid][0]; t2 += wpart[ww][tid][1]; }
    float mu = t1 * (1.0f / 1024.0f);
    float var = t2 * (1.0f / 1024.0f) - mu * mu;
    mu_s[tid] = mu;
    rs_s[tid] = rsqrtf(var + EPS_);
  }
  __syncthreads();

  // LN + direct stores (each thread owns its (m,col) elements; granule-aligned)
  #pragma unroll
  for (int q = 0; q < 4; q++) {
    int col = (w * 4 + q) * 16 + lcol;
    float lw = ldf(lncw, col, fp32), lb = ldf(lncb, col, fp32);
    #pragma unroll
    for (int reg = 0; reg < 4; reg++) {
      int m = quad * 4 + reg;
      float cyv = (buf[m][col] - mu_s[m]) * rs_s[m] * lw + lb;
      out[(size_t)B_ * H_ + (size_t)(b0 + m) * H_ + col] = cyv;
      out[(size_t)(b0 + m) * H_ + col] = obuf[m][col] * tanh_f(cyv);
    }
  }
}

// ---------------------------------------------------------------------------
extern "C" void kernel_launch(void* const* d_in, const int* in_sizes, int n_in,
                              void* d_out, int out_size, void* d_ws, size_t ws_size,
                              hipStream_t stream) {
  const void* input_  = d_in[0];
  const void* hx      = d_in[1];
  const void* cx      = d_in[2];
  const void* topic   = d_in[3];
  const void* w_ih_a  = d_in[4];
  const void* w_ih_b  = d_in[5];
  const void* w_ih_c  = d_in[6];
  const void* w_hh_a  = d_in[7];
  const void* w_hh_b  = d_in[8];
  const void* w_hh_c  = d_in[9];
  const void* th_ih_w = d_in[10];
  const void* th_ih_b = d_in[11];
  const void* th_hh_w = d_in[12];
  const void* th_hh_b = d_in[13];
  const void* ln_i_w  = d_in[14];
  const void* ln_i_b  = d_in[15];
  const void* ln_h_w  = d_in[16];
  const void* ln_h_b  = d_in[17];
  const void* ln_c_w  = d_in[18];
  const void* ln_c_b  = d_in[19];

  float* w = (float*)d_ws;
  float* c1    = w;                          // B*F
  float* c2    = c1 + B_ * F_;
  float* g_i   = c2 + B_ * F_;               // F*F
  float* g_h   = g_i + F_ * F_;
  float* cm_i  = g_h + F_ * F_;              // F
  float* cm_h  = cm_i + F_;
  float* mrs_i = cm_h + F_;                  // B
  float* mrs_h = mrs_i + B_;
  ushort_t* xb = (ushort_t*)(mrs_h + B_);    // B*256 bf16 (A-frag order)
  ushort_t* wbf = xb + (size_t)B_ * 256;     // 256*4096 bf16 (B-frag order)

  hipMemsetAsync(g_i, 0, (size_t)(2 * F_ * F_ + 2 * F_) * sizeof(float), stream);

  k_stageA<<<dim3(NG1 + NPREP + NGRAM), dim3(256), 0, stream>>>(
      input_, hx, w_ih_c, w_hh_c, topic,
      th_ih_w, th_hh_w, th_ih_b, th_hh_b, w_ih_b, w_hh_b,
      w_ih_a, w_hh_a, ln_i_w, ln_h_w,
      wbf, cm_i, cm_h, g_i, g_h, c1, c2);
  k_stats2<<<dim3(512), dim3(256), 0, stream>>>(
      c1, c2, g_i, g_h, cm_i, cm_h, mrs_i, mrs_h, xb);
  k_fused<<<dim3(256), dim3(1024), 0, stream>>>(
      xb, wbf, mrs_i, mrs_h,
      ln_i_w, ln_i_b, ln_h_w, ln_h_b, ln_c_w, ln_c_b, cx, (float*)d_out);
}

// Round 4
// 216.238 us; speedup vs baseline: 1.1602x; 1.0466x over previous
//
#include <hip/hip_runtime.h>

typedef unsigned short ushort_t;
typedef __attribute__((ext_vector_type(8))) short bf8_t;   // 8 x bf16 (4 VGPRs)
typedef __attribute__((ext_vector_type(4))) float f4_t;    // MFMA acc

#define B_   4096
#define IN_  1024
#define H_   1024
#define F_   128
#define G4_  4096
#define EPS_ 1e-5f

#define NG1   512   // gemm1 blocks in stageA
#define NPREP 256   // prep blocks
#define NGRAM 128   // gram blocks

__device__ __forceinline__ float us2f(unsigned short s) {
  union { unsigned int u; float f; } v;
  v.u = ((unsigned int)s) << 16;
  return v.f;
}
__device__ __forceinline__ unsigned short f2us(float f) {  // fp32 -> bf16 RNE
  union { float f; unsigned int u; } v;
  v.f = f;
  unsigned int r = (v.u + 0x7fffu + ((v.u >> 16) & 1u)) >> 16;
  return (unsigned short)r;
}
__device__ __forceinline__ float sigf(float x) { return 1.0f / (1.0f + __expf(-x)); }
__device__ __forceinline__ float tanh_f(float x) { return 1.0f - 2.0f / (1.0f + __expf(2.0f * x)); }

// Runtime input-dtype detection (R1/R2 A/B proved fp32; keep as insurance).
__device__ __forceinline__ int detect_fp32(const void* disc) {
  return ((const unsigned int*)disc)[0] == 0x3F800000u;
}
__device__ __forceinline__ float ldf(const void* p, int i, int fp32) {
  return fp32 ? ((const float*)p)[i] : us2f(((const ushort_t*)p)[i]);
}
__device__ __forceinline__ void ld8(const void* p, int idx, float* o, int fp32) {
  if (fp32) {
    const float4* q = (const float4*)((const float*)p + idx);
    float4 v0 = q[0], v1 = q[1];
    o[0]=v0.x; o[1]=v0.y; o[2]=v0.z; o[3]=v0.w;
    o[4]=v1.x; o[5]=v1.y; o[6]=v1.z; o[7]=v1.w;
  } else {
    uint4 v = *(const uint4*)((const ushort_t*)p + idx);
    const ushort_t* pv = (const ushort_t*)&v;
    #pragma unroll
    for (int i = 0; i < 8; i++) o[i] = us2f(pv[i]);
  }
}
// fast fp32x8 -> bf16x8: round-half-up + v_perm_b32 byte pack (1.5 op/elem)
__device__ __forceinline__ bf8_t cvt8p(const float* f) {
  union { bf8_t v; unsigned int u[4]; } r;
  const unsigned int* ui = (const unsigned int*)f;
  #pragma unroll
  for (int i = 0; i < 4; i++) {
    unsigned int lo = ui[2 * i] + 0x8000u;
    unsigned int hi = ui[2 * i + 1] + 0x8000u;
    r.u[i] = __builtin_amdgcn_perm(hi, lo, 0x07060302u);
  }
  return r.v;
}

// ---------------------------------------------------------------------------
// stageA: three independent jobs fused into one launch for co-residency.
// R9 gemm1 rewrite: stageA was 63us at VALUBusy 11% / VGPR 36 = serialized
// load chains (X ~900cyc HBM + 2x W ~200cyc L2 per kc, no overlap; 32 kc x
// 3.5 blocks/CU ~= 147K cyc = the 63us). Fix:
//  - X tile (16x1024) staged to LDS as bf16 (32KB), 8 coalesced independent
//    32B loads/thread, XOR-swizzled (byte ^= (row&7)<<4) so fragment reads
//    are conflict-free (uniform 8 dwords/bank).
//  - W double-buffered in regs, prefetch distance 2 (static indices only):
//    L2 latency hides under the previous step's cvt+MFMA.
//  - gram's 16KB smem overlaid with the 32KB X-tile in one union.
// ---------------------------------------------------------------------------
__global__ __launch_bounds__(256, 4) void k_stageA(
    const void* __restrict__ X0, const void* __restrict__ X1,
    const void* __restrict__ Wc0, const void* __restrict__ Wc1,
    const void* __restrict__ topic,
    const void* __restrict__ thw0, const void* __restrict__ thw1,
    const void* __restrict__ thb0, const void* __restrict__ thb1,
    const void* __restrict__ wsb0, const void* __restrict__ wsb1,
    const void* __restrict__ Ai, const void* __restrict__ Ah,
    const void* __restrict__ lnwi, const void* __restrict__ lnwh,
    ushort_t* __restrict__ wb,
    float* __restrict__ cm_i, float* __restrict__ cm_h,
    float* __restrict__ g_i, float* __restrict__ g_h,
    float* __restrict__ C0, float* __restrict__ C1)
{
  __shared__ __align__(16) char lds_raw[32768];   // gemm1: bf16 X-tile; gram: As
  int bid = blockIdx.x, tid = threadIdx.x;
  int fp32 = detect_fp32(lnwi);

  if (bid < NG1) {
    int rb = bid >> 1, mat = bid & 1;
    const void* X   = mat ? X1 : X0;
    const void* W   = mat ? Wc1 : Wc0;
    const void* thw = mat ? thw1 : thw0;
    const void* thb = mat ? thb1 : thb0;
    const void* wbp = mat ? wsb1 : wsb0;
    float* C = mat ? C1 : C0;
    int lane = tid & 63, w = tid >> 6;
    int quad = lane >> 4, lcol = lane & 15;
    int brow0 = rb * 16;

    // ---- stage X tile -> LDS bf16, swizzled; 8 coalesced loads/thread ----
    #pragma unroll
    for (int p = 0; p < 8; p++) {
      int fl = p * 2048 + tid * 8;          // flat float idx in [16][1024]
      int r = fl >> 10, cidx = fl & 1023;
      float t8[8];
      ld8(X, (brow0 + r) * IN_ + cidx, t8, fp32);
      bf8_t v = cvt8p(t8);
      int byte = (r * 2048 + cidx * 2) ^ ((r & 7) << 4);
      *(bf8_t*)(lds_raw + byte) = v;
    }
    __syncthreads();

    f4_t acc[2];
    acc[0] = (f4_t){0.f, 0.f, 0.f, 0.f};
    acc[1] = (f4_t){0.f, 0.f, 0.f, 0.f};

    int wrow = w * 32 + lcol;               // t=0 row; t=1 row is +16
    int quad8 = quad * 8;
    int afbase = lcol * 2048 + quad * 16;
    int afxor = (lcol & 7) << 4;

#define AF_(kc) (*(const bf8_t*)(lds_raw + ((afbase + (kc) * 64) ^ afxor)))
#define LOADW_(buf, kc) { \
      ld8(W, (wrow)      * IN_ + (kc) * 32 + quad8, buf[0], fp32); \
      ld8(W, (wrow + 16) * IN_ + (kc) * 32 + quad8, buf[1], fp32); }
#define STEPK_(buf, kc) { \
      bf8_t af_ = AF_(kc); \
      acc[0] = __builtin_amdgcn_mfma_f32_16x16x32_bf16(af_, cvt8p(buf[0]), acc[0], 0, 0, 0); \
      acc[1] = __builtin_amdgcn_mfma_f32_16x16x32_bf16(af_, cvt8p(buf[1]), acc[1], 0, 0, 0); }

    float pb0[2][8], pb1[2][8];
    LOADW_(pb0, 0);
    LOADW_(pb1, 1);
    #pragma unroll
    for (int kc = 0; kc < 32; kc += 2) {
      STEPK_(pb0, kc);
      if (kc + 2 < 32) LOADW_(pb0, kc + 2);
      STEPK_(pb1, kc + 1);
      if (kc + 3 < 32) LOADW_(pb1, kc + 3);
    }
#undef AF_
#undef LOADW_
#undef STEPK_

    float thwf[3][3], thbf[3];
    #pragma unroll
    for (int t = 0; t < 3; t++) {
      thbf[t] = ldf(thb, t, fp32);
      #pragma unroll
      for (int t2 = 0; t2 < 3; t2++) thwf[t][t2] = ldf(thw, t * 3 + t2, fp32);
    }
    float tmpv[4][3];
    #pragma unroll
    for (int reg = 0; reg < 4; reg++) {
      int b = brow0 + quad * 4 + reg;
      float tp0 = ldf(topic, b * 3 + 0, fp32);
      float tp1 = ldf(topic, b * 3 + 1, fp32);
      float tp2 = ldf(topic, b * 3 + 2, fp32);
      #pragma unroll
      for (int t = 0; t < 3; t++)
        tmpv[reg][t] = thbf[t] + tp0 * thwf[t][0] + tp1 * thwf[t][1] + tp2 * thwf[t][2];
    }
    #pragma unroll
    for (int t = 0; t < 2; t++) {
      int f = (w * 2 + t) * 16 + lcol;
      float wv0 = ldf(wbp, f * 3 + 0, fp32);
      float wv1 = ldf(wbp, f * 3 + 1, fp32);
      float wv2 = ldf(wbp, f * 3 + 2, fp32);
      #pragma unroll
      for (int reg = 0; reg < 4; reg++) {
        float sc = tmpv[reg][0] * wv0 + tmpv[reg][1] * wv1 + tmpv[reg][2] * wv2;
        C[(brow0 + quad * 4 + reg) * F_ + f] = acc[t][reg] * sc;
      }
    }
  } else if (bid < NG1 + NPREP) {
    int t = bid - NG1;
    #pragma unroll
    for (int i = 0; i < 16; i++) {
      int e = i * 256 + tid;
      int c = e >> 9, l = (e >> 3) & 63, j = e & 7;
      int k = c * 32 + ((l >> 4) << 3) + j;
      int n = t * 16 + (l & 15);
      float v;
      if (k < 128) v = ldf(Ai, n * F_ + k, fp32) * ldf(lnwi, n, fp32);
      else         v = ldf(Ah, n * F_ + (k - 128), fp32) * ldf(lnwh, n, fp32);
      wb[(size_t)t * 4096 + e] = f2us(v);
    }
    const void* A = (tid < 128) ? Ai : Ah;
    float* cm = (tid < 128) ? cm_i : cm_h;
    int f = tid & 127;
    float s = 0.f;
    #pragma unroll
    for (int i = 0; i < 16; i++) s += ldf(A, (t * 16 + i) * F_ + f, fp32);
    atomicAdd(&cm[f], s);
  } else {
    int g = bid - (NG1 + NPREP);
    int fblk = g & 3, mat = (g >> 2) & 1, z = g >> 3;
    const void* A = mat ? Ah : Ai;
    float* G = mat ? g_h : g_i;
    float (*As)[128] = (float(*)[128])lds_raw;
    int f1_0 = fblk * 32;
    int tf2 = tid & 31, tf1 = tid >> 5;
    float acc[4][4] = {};
    int nbase = z * 256;
    for (int n0 = nbase; n0 < nbase + 256; n0 += 32) {
      #pragma unroll
      for (int j = 0; j < 2; j++) {
        int idx = tid + 256 * j;
        int nn = idx >> 4, f8 = (idx & 15) * 8;
        float t[8];
        ld8(A, (n0 + nn) * F_ + f8, t, fp32);
        #pragma unroll
        for (int i = 0; i < 8; i++) As[nn][f8 + i] = t[i];
      }
      __syncthreads();
      #pragma unroll 4
      for (int nn = 0; nn < 32; nn++) {
        float4 a1 = *(const float4*)&As[nn][f1_0 + 4 * tf1];
        float4 a2 = *(const float4*)&As[nn][4 * tf2];
        const float* x1 = (const float*)&a1;
        const float* x2 = (const float*)&a2;
        #pragma unroll
        for (int i = 0; i < 4; i++)
          #pragma unroll
          for (int j = 0; j < 4; j++) acc[i][j] += x1[i] * x2[j];
      }
      __syncthreads();
    }
    #pragma unroll
    for (int i = 0; i < 4; i++)
      #pragma unroll
      for (int j = 0; j < 4; j++)
        atomicAdd(&G[(f1_0 + 4 * tf1 + i) * F_ + 4 * tf2 + j], acc[i][j]);
  }
}

// ---------------------------------------------------------------------------
// stats2: per-row LN stats via quadratic form
// ---------------------------------------------------------------------------
__global__ __launch_bounds__(256, 4) void k_stats2(
    const float* __restrict__ C0, const float* __restrict__ C1,
    const float* __restrict__ g_i, const float* __restrict__ g_h,
    const float* __restrict__ cm_i, const float* __restrict__ cm_h,
    float* __restrict__ mrs_i, float* __restrict__ mrs_h,
    ushort_t* __restrict__ xb)
{
  int bid = blockIdx.x;
  int rb = bid >> 1, mat = bid & 1;
  const float* C  = mat ? C1 : C0;
  const float* G  = mat ? g_h : g_i;
  const float* cm = mat ? cm_h : cm_i;
  float* mrs = mat ? mrs_h : mrs_i;
  int kbase = mat ? 128 : 0;

  int tid = threadIdx.x;
  int lane = tid & 63, w = tid >> 6;
  int quad = lane >> 4, lcol = lane & 15;
  int b0 = rb * 16;

  __shared__ float p1part[4][16];
  __shared__ float p2s[16];
  __shared__ float rs_s[16];

  bf8_t af[4];
  float p2p = 0.f;
  #pragma unroll
  for (int kc = 0; kc < 4; kc++) {
    int kb = kc * 32 + quad * 8;
    const float4* q = (const float4*)(C + (b0 + lcol) * F_ + kb);
    float4 v0 = q[0], v1 = q[1];
    float a[8] = {v0.x, v0.y, v0.z, v0.w, v1.x, v1.y, v1.z, v1.w};
    af[kc] = cvt8p(a);
    if (w == 0) {
      #pragma unroll
      for (int j = 0; j < 8; j++) p2p += a[j] * cm[kb + j];
    }
  }

  float p1p[4] = {0.f, 0.f, 0.f, 0.f};
  #pragma unroll
  for (int t = 0; t < 2; t++) {
    int colf = (w * 2 + t) * 16 + lcol;
    f4_t acc = {0.f, 0.f, 0.f, 0.f};
    #pragma unroll
    for (int kc = 0; kc < 4; kc++) {
      const float4* qg = (const float4*)(G + colf * F_ + kc * 32 + quad * 8);
      float4 w0 = qg[0], w1 = qg[1];
      float bt[8] = {w0.x, w0.y, w0.z, w0.w, w1.x, w1.y, w1.z, w1.w};
      acc = __builtin_amdgcn_mfma_f32_16x16x32_bf16(af[kc], cvt8p(bt), acc, 0, 0, 0);
    }
    #pragma unroll
    for (int reg = 0; reg < 4; reg++)
      p1p[reg] += acc[reg] * C[(b0 + quad * 4 + reg) * F_ + colf];
  }
  #pragma unroll
  for (int d = 1; d < 16; d <<= 1)
    #pragma unroll
    for (int reg = 0; reg < 4; reg++)
      p1p[reg] += __shfl_xor(p1p[reg], d, 64);
  if (lcol == 0) {
    #pragma unroll
    for (int reg = 0; reg < 4; reg++)
      p1part[w][quad * 4 + reg] = p1p[reg];
  }
  if (w == 0) {
    p2p += __shfl_xor(p2p, 16, 64);
    p2p += __shfl_xor(p2p, 32, 64);
    if (quad == 0) p2s[lcol] = p2p;
  }
  __syncthreads();
  if (tid < 16) {
    float p1 = p1part[0][tid] + p1part[1][tid] + p1part[2][tid] + p1part[3][tid];
    float E2 = p1 * (1.0f / 4096.0f);
    float mu = p2s[tid] * (1.0f / 4096.0f);
    float var = E2 - mu * mu;
    float rs = rsqrtf(var + EPS_);
    rs_s[tid] = rs;
    mrs[b0 + tid] = mu * rs;
  }
  __syncthreads();
  int f = tid & 127, half = tid >> 7;
  ushort_t* xbb = xb + (size_t)rb * 4096;
  int k = kbase + f;
  int c = k >> 5, lq = (k >> 3) & 3, j = k & 7;
  #pragma unroll
  for (int i = 0; i < 8; i++) {
    int r2 = half * 8 + i;
    int lfrag = r2 | (lq << 4);
    xbb[c * 512 + lfrag * 8 + j] = f2us(C[(b0 + r2) * F_ + f] * rs_s[r2]);
  }
}

// ---------------------------------------------------------------------------
// K6 v6: flat phase structure (unchanged from R8 — dropped below stageA).
// ---------------------------------------------------------------------------
__global__ __launch_bounds__(1024) void k_fused(
    const ushort_t* __restrict__ xb, const ushort_t* __restrict__ wb,
    const float* __restrict__ mrs_i, const float* __restrict__ mrs_h,
    const void* __restrict__ lniw, const void* __restrict__ lnib,
    const void* __restrict__ lnhw, const void* __restrict__ lnhb,
    const void* __restrict__ lncw, const void* __restrict__ lncb,
    const void* __restrict__ cx, float* __restrict__ out)
{
  __shared__ float buf[16][1028];    // c pre-LN (written by owning thread)
  __shared__ float obuf[16][1028];   // o-gate
  __shared__ ushort_t xs[4096];      // xb tile (A-fragments)
  __shared__ float wpart[16][16][2];
  __shared__ float mu_s[16], rs_s[16];
  int tid = threadIdx.x;
  int lane = tid & 63, w = tid >> 6;
  int quad = lane >> 4, lcol = lane & 15;
  int b0 = blockIdx.x * 16;
  int fp32 = detect_fp32(lniw);

  // stage xb tile (8KB) into LDS: one 8B copy per thread
  ((unsigned long long*)xs)[tid] =
      ((const unsigned long long*)(xb + (size_t)blockIdx.x * 4096))[tid];

  float mi[4], mh[4];
  #pragma unroll
  for (int reg = 0; reg < 4; reg++) {
    mi[reg] = mrs_i[b0 + quad * 4 + reg];
    mh[reg] = mrs_h[b0 + quad * 4 + reg];
  }
  __syncthreads();

  float s1[4] = {0.f, 0.f, 0.f, 0.f}, s2[4] = {0.f, 0.f, 0.f, 0.f};

  #pragma unroll
  for (int q = 0; q < 4; q++) {
    int cg = w * 4 + q;
    int col = cg * 16 + lcol;
    // issue cx loads early: latency hides under the MFMA block
    float cxv[4];
    #pragma unroll
    for (int reg = 0; reg < 4; reg++)
      cxv[reg] = ldf(cx, (size_t)(b0 + quad * 4 + reg) * H_ + col, fp32);

    f4_t accg[4];
    #pragma unroll
    for (int g = 0; g < 4; g++) accg[g] = (f4_t){0.f, 0.f, 0.f, 0.f};
    // c-outer / g-inner: af from LDS once per c; 4 MFMAs rotate over accs
    #pragma unroll
    for (int c = 0; c < 8; c++) {
      bf8_t af = *(const bf8_t*)&xs[c * 512 + lane * 8];
      #pragma unroll
      for (int g = 0; g < 4; g++) {
        bf8_t bf = *(const bf8_t*)(wb + (size_t)(g * 64 + cg) * 4096 + c * 512 + lane * 8);
        accg[g] = __builtin_amdgcn_mfma_f32_16x16x32_bf16(af, bf, accg[g], 0, 0, 0);
      }
    }
    float liw0 = ldf(lniw, 0 * H_ + col, fp32), lib0 = ldf(lnib, 0 * H_ + col, fp32);
    float lhw0 = ldf(lnhw, 0 * H_ + col, fp32), lhb0 = ldf(lnhb, 0 * H_ + col, fp32);
    float liw1 = ldf(lniw, 1 * H_ + col, fp32), lib1 = ldf(lnib, 1 * H_ + col, fp32);
    float lhw1 = ldf(lnhw, 1 * H_ + col, fp32), lhb1 = ldf(lnhb, 1 * H_ + col, fp32);
    float liw2 = ldf(lniw, 2 * H_ + col, fp32), lib2 = ldf(lnib, 2 * H_ + col, fp32);
    float lhw2 = ldf(lnhw, 2 * H_ + col, fp32), lhb2 = ldf(lnhb, 2 * H_ + col, fp32);
    float liw3 = ldf(lniw, 3 * H_ + col, fp32), lib3 = ldf(lnib, 3 * H_ + col, fp32);
    float lhw3 = ldf(lnhw, 3 * H_ + col, fp32), lhb3 = ldf(lnhb, 3 * H_ + col, fp32);
    #pragma unroll
    for (int reg = 0; reg < 4; reg++) {
      int m = quad * 4 + reg;
      float gi = accg[0][reg] + lib0 + lhb0 - mi[reg] * liw0 - mh[reg] * lhw0;
      float gf = accg[1][reg] + lib1 + lhb1 - mi[reg] * liw1 - mh[reg] * lhw1;
      float gg = accg[2][reg] + lib2 + lhb2 - mi[reg] * liw2 - mh[reg] * lhw2;
      float go = accg[3][reg] + lib3 + lhb3 - mi[reg] * liw3 - mh[reg] * lhw3;
      float iv = sigf(gi), fv = sigf(gf), gv = tanh_f(gg), ov = sigf(go);
      float cval = fv * cxv[reg] + iv * gv;
      buf[m][col] = cval;
      obuf[m][col] = ov;
      s1[reg] += cval;
      s2[reg] += cval * cval;
    }
  }

  // cy-LN stats reduce
  #pragma unroll
  for (int d = 1; d < 16; d <<= 1) {
    #pragma unroll
    for (int reg = 0; reg < 4; reg++) {
      s1[reg] += __shfl_xor(s1[reg], d, 64);
      s2[reg] += __shfl_xor(s2[reg], d, 64);
    }
  }
  if (lcol == 0) {
    #pragma unroll
    for (int reg = 0; reg < 4; reg++) {
      wpart[w][quad * 4 + reg][0] = s1[reg];
      wpart[w][quad * 4 + reg][1] = s2[reg];
    }
  }
  __syncthreads();
  if (tid < 16) {
    float t1 = 0.f, t2 = 0.f;
    #pragma unroll
    for (int ww = 0; ww < 16; ww++) { t1 += wpart[ww][tid][0]; t2 += wpart[ww][tid][1]; }
    float mu = t1 * (1.0f / 1024.0f);
    float var = t2 * (1.0f / 1024.0f) - mu * mu;
    mu_s[tid] = mu;
    rs_s[tid] = rsqrtf(var + EPS_);
  }
  __syncthreads();

  // LN + direct stores (each thread owns its (m,col) elements; granule-aligned)
  #pragma unroll
  for (int q = 0; q < 4; q++) {
    int col = (w * 4 + q) * 16 + lcol;
    float lw = ldf(lncw, col, fp32), lb = ldf(lncb, col, fp32);
    #pragma unroll
    for (int reg = 0; reg < 4; reg++) {
      int m = quad * 4 + reg;
      float cyv = (buf[m][col] - mu_s[m]) * rs_s[m] * lw + lb;
      out[(size_t)B_ * H_ + (size_t)(b0 + m) * H_ + col] = cyv;
      out[(size_t)(b0 + m) * H_ + col] = obuf[m][col] * tanh_f(cyv);
    }
  }
}

// ---------------------------------------------------------------------------
extern "C" void kernel_launch(void* const* d_in, const int* in_sizes, int n_in,
                              void* d_out, int out_size, void* d_ws, size_t ws_size,
                              hipStream_t stream) {
  const void* input_  = d_in[0];
  const void* hx      = d_in[1];
  const void* cx      = d_in[2];
  const void* topic   = d_in[3];
  const void* w_ih_a  = d_in[4];
  const void* w_ih_b  = d_in[5];
  const void* w_ih_c  = d_in[6];
  const void* w_hh_a  = d_in[7];
  const void* w_hh_b  = d_in[8];
  const void* w_hh_c  = d_in[9];
  const void* th_ih_w = d_in[10];
  const void* th_ih_b = d_in[11];
  const void* th_hh_w = d_in[12];
  const void* th_hh_b = d_in[13];
  const void* ln_i_w  = d_in[14];
  const void* ln_i_b  = d_in[15];
  const void* ln_h_w  = d_in[16];
  const void* ln_h_b  = d_in[17];
  const void* ln_c_w  = d_in[18];
  const void* ln_c_b  = d_in[19];

  float* w = (float*)d_ws;
  float* c1    = w;                          // B*F
  float* c2    = c1 + B_ * F_;
  float* g_i   = c2 + B_ * F_;               // F*F
  float* g_h   = g_i + F_ * F_;
  float* cm_i  = g_h + F_ * F_;              // F
  float* cm_h  = cm_i + F_;
  float* mrs_i = cm_h + F_;                  // B
  float* mrs_h = mrs_i + B_;
  ushort_t* xb = (ushort_t*)(mrs_h + B_);    // B*256 bf16 (A-frag order)
  ushort_t* wbf = xb + (size_t)B_ * 256;     // 256*4096 bf16 (B-frag order)

  hipMemsetAsync(g_i, 0, (size_t)(2 * F_ * F_ + 2 * F_) * sizeof(float), stream);

  k_stageA<<<dim3(NG1 + NPREP + NGRAM), dim3(256), 0, stream>>>(
      input_, hx, w_ih_c, w_hh_c, topic,
      th_ih_w, th_hh_w, th_ih_b, th_hh_b, w_ih_b, w_hh_b,
      w_ih_a, w_hh_a, ln_i_w, ln_h_w,
      wbf, cm_i, cm_h, g_i, g_h, c1, c2);
  k_stats2<<<dim3(512), dim3(256), 0, stream>>>(
      c1, c2, g_i, g_h, cm_i, cm_h, mrs_i, mrs_h, xb);
  k_fused<<<dim3(256), dim3(1024), 0, stream>>>(
      xb, wbf, mrs_i, mrs_h,
      ln_i_w, ln_i_b, ln_h_w, ln_h_b, ln_c_w, ln_c_b, cx, (float*)d_out);
}